// Round 16
// baseline (68.696 us; speedup 1.0000x reference)
//
#include <hip/hip_runtime.h>

typedef __bf16 bf16;
typedef __bf16 bf16x8 __attribute__((ext_vector_type(8)));
typedef __bf16 bf16x4 __attribute__((ext_vector_type(4)));
typedef __bf16 bf16x2 __attribute__((ext_vector_type(2)));
typedef float  f32x4  __attribute__((ext_vector_type(4)));
typedef float  f32x16 __attribute__((ext_vector_type(16)));
typedef unsigned int uint32;

constexpr int DIM_  = 1024;
constexpr int NH    = 16;
constexpr int CHD   = 32;     // current head dim
constexpr int CDIM  = 512;    // NH * CHD
constexpr int CQ    = 1536;   // 3 * CDIM
constexpr int NSEQ  = 2048;
constexpr int M_    = 4096;   // B * N
constexpr float ATT_SCALE = 0.17677669529663687f; // (64^-0.5)/sqrt(0.5)
constexpr float QS_LOG2 = ATT_SCALE * 1.4426950408889634f; // fold log2(e): softmax in exp2 domain

__device__ inline void gload16(const bf16* g, bf16* l) {
    __builtin_amdgcn_global_load_lds((const __attribute__((address_space(1))) void*)g,
                                     (__attribute__((address_space(3))) void*)l, 16, 0, 0);
}

// ---------------- fused cast: x, w_qkv, w_proj slice -> bf16 (one launch) ----------------
constexpr int NX4 = M_ * DIM_ / 4;        // 1048576
constexpr int NW4 = CQ * DIM_ / 4;        // 393216
constexpr int NP4 = DIM_ * (CDIM / 4);    // 131072
__global__ void cast_fused(const float* __restrict__ x, const float* __restrict__ wq,
                           const float* __restrict__ wp, bf16* __restrict__ xb,
                           bf16* __restrict__ wqb, bf16* __restrict__ wpb) {
    int i = blockIdx.x * blockDim.x + threadIdx.x;   // exactly NX4+NW4+NP4 threads
    const float4* src;
    bf16x4* dst;
    if (i < NX4) {
        src = reinterpret_cast<const float4*>(x) + i;
        dst = reinterpret_cast<bf16x4*>(xb) + i;
    } else if (i < NX4 + NW4) {
        int j = i - NX4;
        src = reinterpret_cast<const float4*>(wq) + j;
        dst = reinterpret_cast<bf16x4*>(wqb) + j;
    } else {
        int j = i - (NX4 + NW4);
        int c = j >> 7, j4 = j & 127;
        src = reinterpret_cast<const float4*>(wp + c * DIM_) + j4;
        dst = reinterpret_cast<bf16x4*>(wpb + c * CDIM) + j4;
    }
    float4 v = *src;
    bf16x4 o = { (bf16)v.x, (bf16)v.y, (bf16)v.z, (bf16)v.w };
    *dst = o;
}

// ---------------- NT GEMM: C[m][n] = sum_k A[m][k] * B[n][k] ----------------
// 128x64 tile, 4 waves (2x2), BK=64, XOR chunk-swizzle (unchanged from R15).
template<int KDIM, int MODE>
__launch_bounds__(256)
__global__ void gemm_nt(const bf16* __restrict__ A, const bf16* __restrict__ Bm,
                        bf16* __restrict__ qbo, bf16* __restrict__ kbo, bf16* __restrict__ vto,
                        float* __restrict__ Cf, const float* __restrict__ bias) {
    __shared__ __align__(16) bf16 SMEM[24576];   // As 2x8192 | Bs 2x4096 (48KB); bounce reuse
    bf16* As = SMEM;             // [buf][row 0..127][chunk' 0..7]  (chunk = 8 bf16 = 16B)
    bf16* Bs = SMEM + 16384;     // [buf][row 0..63][chunk' 0..7]
    const int tid = threadIdx.x;
    const int w = tid >> 6, lane = tid & 63;
    const int m0 = blockIdx.x * 128, n0 = blockIdx.y * 64;
    const int wr = (w >> 1) * 64, wc = (w & 1) * 32;
    const int cl = lane & 15, hi = lane >> 4;    // fragment row / k-group
    const int swz = cl & 7;                      // read-side XOR

    const int srow = lane >> 3, schk = (lane & 7) ^ (lane >> 3);
    const bf16* gaA = A  + (m0 + srow) * KDIM + schk * 8;
    const bf16* gbB = Bm + (n0 + srow) * KDIM + schk * 8;

    constexpr int KT = KDIM / 64;

    auto stage = [&](int kt, int b) {
#pragma unroll
        for (int i = 0; i < 4; ++i)
            gload16(gaA + (w * 4 + i) * 8 * KDIM + kt * 64, As + b * 8192 + (w * 4 + i) * 512);
#pragma unroll
        for (int i = 0; i < 2; ++i)
            gload16(gbB + (w * 2 + i) * 8 * KDIM + kt * 64, Bs + b * 4096 + (w * 2 + i) * 512);
    };
    stage(0, 0);
    __syncthreads();

    f32x4 acc[4][2] = {};

    for (int kt = 0; kt < KT; ++kt) {
        if (kt + 1 < KT) stage(kt + 1, (kt + 1) & 1);
        const bf16* as = As + (kt & 1) * 8192;
        const bf16* bs = Bs + (kt & 1) * 4096;
#pragma unroll
        for (int kh = 0; kh < 2; ++kh) {
            const int ck = ((kh * 4 + hi) ^ swz) * 8;   // swizzled chunk offset (elems)
            bf16x8 af[4], bfr[2];
#pragma unroll
            for (int i = 0; i < 4; ++i)
                af[i]  = *reinterpret_cast<const bf16x8*>(as + (wr + i * 16 + cl) * 64 + ck);
#pragma unroll
            for (int j = 0; j < 2; ++j)
                bfr[j] = *reinterpret_cast<const bf16x8*>(bs + (wc + j * 16 + cl) * 64 + ck);
#pragma unroll
            for (int i = 0; i < 4; ++i)
#pragma unroll
                for (int j = 0; j < 2; ++j)
                    acc[i][j] = __builtin_amdgcn_mfma_f32_16x16x32_bf16(af[i], bfr[j], acc[i][j], 0, 0, 0);
        }
        __syncthreads();
    }

    const int rg = hi * 4;   // D layout: row=(l>>4)*4+r, col=l&15
    if constexpr (MODE == 2) {
#pragma unroll
        for (int i = 0; i < 4; ++i)
#pragma unroll
            for (int j = 0; j < 2; ++j) {
                const int row = m0 + wr + i * 16 + rg;
                const int col = n0 + wc + j * 16 + cl;
                const float bv = bias[col];
#pragma unroll
                for (int r = 0; r < 4; ++r)
                    Cf[(row + r) * DIM_ + col] = acc[i][j][r] + bv;
            }
    } else {
        const int sec = n0 >> 9;   // block-uniform: 0=q 1=k 2=v
        if (sec == 2) {
#pragma unroll
            for (int i = 0; i < 4; ++i)
#pragma unroll
                for (int j = 0; j < 2; ++j) {
                    const int row = m0 + wr + i * 16 + rg;
                    const int col = n0 + wc + j * 16 + cl;
                    const int rem = col & 511;
                    const int h = rem >> 5, d = rem & 31;
                    const int bb = row >> 11, pos = row & 2047;
                    const int bh = bb * NH + h;
                    bf16x4 st;
#pragma unroll
                    for (int r = 0; r < 4; ++r) st[r] = (bf16)acc[i][j][r];
                    *reinterpret_cast<bf16x4*>(vto + (bh * CHD + d) * NSEQ + pos) = st;
                }
        } else {
            // bounce through LDS -> coalesced b128 stores
            const float sc = sec ? 1.0f : QS_LOG2;
            __syncthreads();   // done reading As/Bs
#pragma unroll
            for (int i = 0; i < 4; ++i)
#pragma unroll
                for (int j = 0; j < 2; ++j)
#pragma unroll
                    for (int r = 0; r < 4; ++r)
                        SMEM[(wr + i * 16 + rg + r) * 72 + wc + j * 16 + cl] =
                            (bf16)(acc[i][j][r] * sc);
            __syncthreads();
            const int row = tid >> 1, ch = (tid & 1) * 32;
            const int m = m0 + row, bb = m >> 11, pos = m & 2047;
            const int col0 = n0 + ch;
            const int h = (col0 & 511) >> 5;
            bf16* dst = (sec ? kbo : qbo) + ((bb * NH + h) * NSEQ + pos) * CHD;
#pragma unroll
            for (int v4 = 0; v4 < 4; ++v4)
                *reinterpret_cast<bf16x8*>(dst + v4 * 8) =
                    *reinterpret_cast<const bf16x8*>(SMEM + row * 72 + ch + v4 * 8);
        }
    }
}

// pack two f32 -> dword of two bf16 (v_cvt_pk_bf16_f32)
__device__ inline uint32 pkbf(float lo, float hi) {
    bf16x2 t = { (bf16)lo, (bf16)hi };
    return __builtin_bit_cast(uint32, t);
}

// ---------------- flash attention v10: KVBLK=128 (half the barriers), fused chunk softmax ----------------
// Grid 512 blocks x 512 thr (8 waves). Waves 0-3: q strips p=0..3, kv[0:1024);
// waves 4-7: same strips, kv[1024:2048). Per wave: 32 q-rows, KV tile 128 -> only 8
// barrier/drain cycles (vs 16 at KVBLK=64): halves the per-tile vmcnt(0) lockstep stall.
// Per tile: 4 h-blocks of 32 kv, each {QK(2 MFMA swapped) -> per-8-chunk fused
// exp2->rowsum->cvt_pk->permlane pack -> PV MFMA}. Zero-shift softmax (bounded logits).
// K/V staged as frag-blobs via global_load_lds, double-buffered (2x16KB per half).
// kv halves merged through LDS at the end (plain add; shared zero shift).
__launch_bounds__(512, 4)
__global__ void flash_kernel(const bf16* __restrict__ qb, const bf16* __restrict__ kb,
                             const bf16* __restrict__ vt, bf16* __restrict__ outb) {
    __shared__ __align__(16) char smem[65536];  // [half][par][K 8KB | V 8KB]; merge reuse
    const int tid = threadIdx.x;
    const int w = tid >> 6, lane = tid & 63;
    const int lq = lane & 31, hi = lane >> 5;
    const int p = w & 3, half = w >> 2;

    const int blin = blockIdx.x;                 // XCD swizzle: 4 heads per XCD
    const int xcd = blin & 7, within = blin >> 3;
    const int head = xcd * 4 + (within >> 4);
    const int qblk = within & 15;
    const int q0 = qblk * 128 + p * 32;

    const bf16* Q = qb + head * (NSEQ * CHD);
    const bf16* K = kb + head * (NSEQ * CHD);
    const bf16* V = vt + head * (CHD * NSEQ);    // V^T: [d][pos]

    // Q B-fragments (kc=0,1): lane -> Q[q0+lq][16*kc + 8*hi + j]
    const bf16x8 qf0 = *reinterpret_cast<const bf16x8*>(Q + (q0 + lq) * CHD + hi * 8);
    const bf16x8 qf1 = *reinterpret_cast<const bf16x8*>(Q + (q0 + lq) * CHD + 16 + hi * 8);

    char* base = smem + half * 32768;
    // staging: strip-wave p stages K rows p*32..p*32+31 (both kc chunks) and V kv-slices
    // 2p,2p+1 of its half's current 128-tile (4 x 1KB blobs per wave per tile).
    const bf16* srcK = K + (half * 1024 + p * 32 + lq) * CHD + hi * 8;
    const bf16* srcV = V + lq * NSEQ + half * 1024 + p * 32 + hi * 8;

    auto stage = [&](int t) {
        char* b = base + (t & 1) * 16384;
        gload16(srcK + t * 128 * CHD,      (bf16*)(b + (2 * p) * 1024));      // K blob h=p, kc=0
        gload16(srcK + t * 128 * CHD + 16, (bf16*)(b + (2 * p + 1) * 1024));  // K blob h=p, kc=1
        gload16(srcV + t * 128,            (bf16*)(b + 8192 + (2 * p) * 1024));     // V blob 2p
        gload16(srcV + t * 128 + 16,       (bf16*)(b + 8192 + (2 * p + 1) * 1024)); // V blob 2p+1
    };
    stage(0);
    __syncthreads();

    f32x16 o = {};
    float rs[4] = {};
    const f32x16 zero16 = {};

    for (int t = 0; t < 8; ++t) {
        if (t < 7) stage(t + 1);
        char* buf = base + (t & 1) * 16384;
#pragma unroll
        for (int h = 0; h < 4; ++h) {
            // QK^T (swapped): s = S^T[kv 32h..+32][q]; lane: q=lq, kv=32h+(r&3)+8(r>>2)+4hi
            const bf16x8 k0 = *reinterpret_cast<const bf16x8*>(buf + (2 * h) * 1024 + lane * 16);
            const bf16x8 k1 = *reinterpret_cast<const bf16x8*>(buf + (2 * h + 1) * 1024 + lane * 16);
            __builtin_amdgcn_s_setprio(1);
            f32x16 s = __builtin_amdgcn_mfma_f32_32x32x16_bf16(k0, qf0, zero16, 0, 0, 0);
            s = __builtin_amdgcn_mfma_f32_32x32x16_bf16(k1, qf1, s, 0, 0, 0);
            __builtin_amdgcn_s_setprio(0);

            // fused per-8-chunk: exp2 -> rowsum -> pack -> PV (short dep chains, small live set)
#pragma unroll
            for (int cc = 0; cc < 2; ++cc) {
                const int b8 = cc * 8;
                float e[8];
#pragma unroll
                for (int j = 0; j < 8; ++j) e[j] = __builtin_amdgcn_exp2f(s[b8 + j]);
#pragma unroll
                for (int j = 0; j < 8; ++j) rs[j & 3] += e[j];
                uint32 u0 = pkbf(e[0], e[1]);
                uint32 u1 = pkbf(e[2], e[3]);
                uint32 u2 = pkbf(e[4], e[5]);
                uint32 u3 = pkbf(e[6], e[7]);
                asm volatile("v_permlane32_swap_b32 %0, %1" : "+v"(u0), "+v"(u2));
                asm volatile("v_permlane32_swap_b32 %0, %1" : "+v"(u1), "+v"(u3));
                union { uint32 u[4]; bf16x8 v; } pb;
                pb.u[0] = u0; pb.u[1] = u1; pb.u[2] = u2; pb.u[3] = u3;
                const bf16x8 vf = *reinterpret_cast<const bf16x8*>(buf + 8192 + (2 * h + cc) * 1024 + lane * 16);
                __builtin_amdgcn_s_setprio(1);
                o = __builtin_amdgcn_mfma_f32_32x32x16_bf16(vf, pb.v, o, 0, 0, 0);
                __builtin_amdgcn_s_setprio(0);
            }
        }
        __syncthreads();
    }

    // row-sum over the hi pair (uniform across pair afterwards)
    float ls = (rs[0] + rs[1]) + (rs[2] + rs[3]);
    ls += __shfl_xor(ls, 32);

    // cross-wave merge of kv halves through LDS (plain add: both halves share zero shift)
    float* Mo = (float*)(smem + p * 4608);
    float* Ml = (float*)(smem + p * 4608 + 4096);
    if (half) {
#pragma unroll
        for (int r = 0; r < 16; ++r) Mo[r * 64 + lane] = o[r];
        Ml[lane] = ls;
    }
    __syncthreads();
    if (!half) {
        const float inv = 1.f / (ls + Ml[lane]);
        const int bb = head >> 4, hh = head & 15;
        const int row = bb * NSEQ + q0 + lq;
        const int colb = hh * CHD;
#pragma unroll
        for (int rq = 0; rq < 4; ++rq) {
            bf16x4 st;
#pragma unroll
            for (int ri = 0; ri < 4; ++ri)
                st[ri] = (bf16)((o[rq * 4 + ri] + Mo[(rq * 4 + ri) * 64 + lane]) * inv);
            *reinterpret_cast<bf16x4*>(outb + row * CDIM + colb + rq * 8 + hi * 4) = st;
        }
    }
}

// ---------------- launch ----------------
extern "C" void kernel_launch(void* const* d_in, const int* in_sizes, int n_in,
                              void* d_out, int out_size, void* d_ws, size_t ws_size,
                              hipStream_t stream) {
    const float* x      = (const float*)d_in[0];
    const float* w_qkv  = (const float*)d_in[1];
    const float* w_proj = (const float*)d_in[2];
    const float* b_proj = (const float*)d_in[3];
    float* out = (float*)d_out;

    char* ws = (char*)d_ws;
    bf16* xb  = (bf16*)(ws);                         // 4096x1024      (8 MiB)
    bf16* wqb = (bf16*)(ws + 8388608);               // 1536x1024      (3 MiB)
    bf16* wpb = (bf16*)(ws + 11534336);              // 1024x512       (1 MiB)
    bf16* qb  = (bf16*)(ws + 25165824);              // 32x2048x32     (4 MiB)
    bf16* kb  = (bf16*)(ws + 29360128);              // 32x2048x32     (4 MiB)
    bf16* vt  = (bf16*)(ws + 33554432);              // 32x32x2048     (4 MiB)
    bf16* ob  = (bf16*)(ws + 37748736);              // 4096x512       (4 MiB)

    cast_fused<<<(NX4 + NW4 + NP4) / 256, 256, 0, stream>>>(x, w_qkv, w_proj, xb, wqb, wpb);

    gemm_nt<DIM_, 1><<<dim3(32, 24), 256, 0, stream>>>(xb, wqb, qb, kb, vt, nullptr, nullptr);

    flash_kernel<<<512, 512, 0, stream>>>(qb, kb, vt, ob);

    gemm_nt<CDIM, 2><<<dim3(32, 16), 256, 0, stream>>>(ob, wpb, nullptr, nullptr, nullptr, out, b_proj);
}